// Round 6
// baseline (973.371 us; speedup 1.0000x reference)
//
#include <hip/hip_runtime.h>

#define NTAG 48
#define SEQ 1024
#define NBATCH 512
#define NEG_INF (-3.402823466e+38f)

// broadcast lane `lane`'s value of v to all lanes (compile-time lane -> v_readlane imm)
__device__ __forceinline__ float rl_f32(float v, int lane) {
    return __int_as_float(__builtin_amdgcn_readlane(__float_as_int(v), lane));
}

// guaranteed single-instruction 3-input max (exact; max has no rounding)
__device__ __forceinline__ float max3(float a, float b, float c) {
    float d;
    asm("v_max3_f32 %0, %1, %2, %3" : "=v"(d) : "v"(a), "v"(b), "v"(c));
    return d;
}

__global__ __launch_bounds__(64, 1) void crf_viterbi_kernel(
    const float* __restrict__ em,      // [B, S, T]
    const float* __restrict__ trans,   // [T, T]
    const float* __restrict__ start,   // [T]
    const float* __restrict__ endt,    // [T]
    int* __restrict__ out,             // [B, S] tags (int32)
    float* __restrict__ srows)         // [B, S, T] score rows (workspace)
{
    const int b  = blockIdx.x;
    const int j  = threadIdx.x;                 // 0..63; tags 0..47 valid
    const int jj = (j < NTAG) ? j : (NTAG - 1); // clamped for safe loads

    __shared__ float Ttr[NTAG * NTAG];  // Ttr[c*48+i] = T[i][c]
    __shared__ int obuf[SEQ];

    // fill transposed T (2304 elems / 64 lanes = 36 each)
#pragma unroll
    for (int k = 0; k < (NTAG * NTAG + 63) / 64; ++k) {
        int idx = k * 64 + j;
        if (idx < NTAG * NTAG) {
            int i = idx / NTAG, c = idx % NTAG;
            Ttr[c * NTAG + i] = trans[idx];
        }
    }

    // transition column j: trg[i] = T[i][j]
    float trg[NTAG];
#pragma unroll
    for (int i = 0; i < NTAG; ++i) trg[i] = trans[i * NTAG + jj];

    const float* emb = em + (size_t)b * SEQ * NTAG;
    float* srb = srows + (size_t)b * SEQ * NTAG;

    float score = start[jj] + emb[jj];          // S_0[j]
    if (j < NTAG) srb[j] = score;

    // emission prefetch depth 2
    float em_p1 = emb[1 * NTAG + jj];
    float em_p2 = emb[2 * NTAG + jj];

    // ---------------- forward: value-only (no argmax) ----------------
    for (int t = 1; t < SEQ; ++t) {
        float em_j = em_p1;
        em_p1 = em_p2;
        int tn = (t + 2 < SEQ) ? (t + 2) : (SEQ - 1);
        em_p2 = emb[tn * NTAG + jj];

        // 48 candidates folded straight into a max3 tree (no live cand array)
        float l1[16];
#pragma unroll
        for (int k = 0; k < 16; ++k) {
            float c0 = rl_f32(score, 3 * k)     + trg[3 * k];
            float c1 = rl_f32(score, 3 * k + 1) + trg[3 * k + 1];
            float c2 = rl_f32(score, 3 * k + 2) + trg[3 * k + 2];
            l1[k] = max3(c0, c1, c2);
        }
        float l2[6];
        l2[0] = max3(l1[0],  l1[1],  l1[2]);
        l2[1] = max3(l1[3],  l1[4],  l1[5]);
        l2[2] = max3(l1[6],  l1[7],  l1[8]);
        l2[3] = max3(l1[9],  l1[10], l1[11]);
        l2[4] = max3(l1[12], l1[13], l1[14]);
        l2[5] = l1[15];
        float m0 = max3(l2[0], l2[1], l2[2]);
        float m1 = max3(l2[3], l2[4], l2[5]);
        float best = fmaxf(m0, m1);

        score = best + em_j;                     // S_t[j], exact ref order
        if (j < NTAG) srb[(size_t)t * NTAG + j] = score;
    }

    // ---------------- final tag: argmax_j(S_{S-1}[j] + end[j]) ----------------
    float fs = (j < NTAG) ? (score + endt[jj]) : NEG_INF;
    float mx = fs;
    mx = fmaxf(mx, __shfl_xor(mx, 32, 64));
    mx = fmaxf(mx, __shfl_xor(mx, 16, 64));
    mx = fmaxf(mx, __shfl_xor(mx,  8, 64));
    mx = fmaxf(mx, __shfl_xor(mx,  4, 64));
    mx = fmaxf(mx, __shfl_xor(mx,  2, 64));
    mx = fmaxf(mx, __shfl_xor(mx,  1, 64));
    unsigned long long bl = __ballot(fs == mx);
    int jt = __ffsll(bl) - 1;                    // first-max (lowest j), exact

    if (j == 0) obuf[SEQ - 1] = jt;
    __syncthreads();                             // Ttr + obuf visible (1 wave: cheap)

    // ---------------- backtrace: re-derive argmax from stored rows ----------------
    // step t (t=S-1..1): j_{t-1} = argmax_i( S_{t-1}[i] + T[i][j_t] ), first-max
    float cur[8], nxt[8];
    int r = SEQ - 2;                             // row used at step t is r = t-1
#pragma unroll
    for (int k = 0; k < 8; ++k)
        cur[k] = srb[(size_t)(r - k) * NTAG + jj];

    int t = SEQ - 1;
    while (t >= 1) {
        int n = (t >= 8) ? 8 : t;
        int r2 = r - 8;
#pragma unroll
        for (int k = 0; k < 8; ++k)
            if (r2 - k >= 0) nxt[k] = srb[(size_t)(r2 - k) * NTAG + jj];

#pragma unroll
        for (int k = 0; k < 8; ++k) {
            if (k < n) {
                float tv = Ttr[jt * NTAG + jj];          // T[i][jt], lane i
                float v  = (j < NTAG) ? (cur[k] + tv) : NEG_INF;
                float m  = v;
                m = fmaxf(m, __shfl_xor(m, 32, 64));
                m = fmaxf(m, __shfl_xor(m, 16, 64));
                m = fmaxf(m, __shfl_xor(m,  8, 64));
                m = fmaxf(m, __shfl_xor(m,  4, 64));
                m = fmaxf(m, __shfl_xor(m,  2, 64));
                m = fmaxf(m, __shfl_xor(m,  1, 64));
                unsigned long long b2 = __ballot(v == m);
                jt = __ffsll(b2) - 1;                    // lowest i on ties
                if (j == 0) obuf[t - 1 - k] = jt;
            }
        }
        t -= n; r -= 8;
#pragma unroll
        for (int k = 0; k < 8; ++k) cur[k] = nxt[k];
    }

    __syncthreads();

    // coalesced int32 dump of the batch's path
    int* outb = out + (size_t)b * SEQ;
#pragma unroll
    for (int t0 = 0; t0 < SEQ / 64; ++t0)
        outb[t0 * 64 + j] = obuf[t0 * 64 + j];
}

extern "C" void kernel_launch(void* const* d_in, const int* in_sizes, int n_in,
                              void* d_out, int out_size, void* d_ws, size_t ws_size,
                              hipStream_t stream) {
    const float* em    = (const float*)d_in[0];
    // d_in[1] = mask (int32), unused — matches reference
    const float* trans = (const float*)d_in[2];
    const float* start = (const float*)d_in[3];
    const float* endt  = (const float*)d_in[4];
    int* out = (int*)d_out;
    float* srows = (float*)d_ws;   // needs B*S*T*4 = 100,663,296 bytes

    crf_viterbi_kernel<<<NBATCH, 64, 0, stream>>>(em, trans, start, endt, out, srows);
}

// Round 8
// 828.712 us; speedup vs baseline: 1.1746x; 1.1746x over previous
//
#include <hip/hip_runtime.h>

#define NTAG 48
#define SEQ 1024
#define NBATCH 512
#define CH 128                    // steps (rows) per LDS chunk
#define NCH (SEQ / CH)            // 8
#define CHF (CH * NTAG)           // 6144 floats per chunk
#define NISS (CHF * 4 / 1024)     // 24 global_load_lds issues per chunk (1KB each)
#define NEG_INF (-3.402823466e+38f)

// broadcast lane `lane`'s value of v to all lanes (compile-time lane -> v_readlane imm)
__device__ __forceinline__ float rl_f32(float v, int lane) {
    return __int_as_float(__builtin_amdgcn_readlane(__float_as_int(v), lane));
}

// single-instruction 3-input max (exact; max has no rounding)
__device__ __forceinline__ float max3(float a, float b, float c) {
    float d;
    asm("v_max3_f32 %0, %1, %2, %3" : "=v"(d) : "v"(a), "v"(b), "v"(c));
    return d;
}

// async global->LDS, 16B per lane; LDS dest = base + lane*16 (linear), global src per-lane
#define GLDS16(gp, lp)                                                                   \
    __builtin_amdgcn_global_load_lds((const __attribute__((address_space(1))) void*)(gp),\
                                     (__attribute__((address_space(3))) void*)(lp),      \
                                     16, 0, 0)

__global__ __launch_bounds__(64, 1) void crf_viterbi_kernel(
    const float* __restrict__ em,      // [B, S, T]
    const float* __restrict__ trans,   // [T, T]
    const float* __restrict__ start,   // [T]
    const float* __restrict__ endt,    // [T]
    int* __restrict__ out,             // [B, S] tags (int32)
    float* __restrict__ srows)         // [B, S, T] score rows (workspace)
{
    const int b  = blockIdx.x;
    const int j  = threadIdx.x;                 // 0..63; tags 0..47 valid
    const int jj = (j < NTAG) ? j : (NTAG - 1); // clamped for safe loads

    __shared__ float stage[2][CHF];     // 2 x 24KB staging (em fwd / srows bwd)
    __shared__ float Ttr[NTAG * NTAG];  // Ttr[c*48+i] = T[i][c]
    __shared__ int obuf[SEQ];

    // fill transposed T (2304 elems / 64 lanes = 36 each)
#pragma unroll
    for (int k = 0; k < (NTAG * NTAG + 63) / 64; ++k) {
        int idx = k * 64 + j;
        if (idx < NTAG * NTAG) {
            int i = idx / NTAG, c = idx % NTAG;
            Ttr[c * NTAG + i] = trans[idx];
        }
    }

    // transition column j in regs: trg[i] = T[i][j]
    float trg[NTAG];
#pragma unroll
    for (int i = 0; i < NTAG; ++i) trg[i] = trans[i * NTAG + jj];

    const float* emb = em + (size_t)b * SEQ * NTAG;
    float* srb = srows + (size_t)b * SEQ * NTAG;

    // ---- prologue: stage em chunk 0 ----
#pragma unroll
    for (int k = 0; k < NISS; ++k)
        GLDS16(emb + k * 256 + j * 4, &stage[0][k * 256]);
    asm volatile("s_waitcnt vmcnt(0)" ::: "memory");

    float score = start[jj] + stage[0][jj];     // S_0[j]
    if (j < NTAG) srb[j] = score;

    // ---------------- forward: value-only, vmem-free inner loop ----------------
    int cb = 0;
    for (int c = 0; c < NCH; ++c) {
        if (c + 1 < NCH) {
            const float* gs = emb + (size_t)(c + 1) * CHF;
#pragma unroll
            for (int k = 0; k < NISS; ++k)
                GLDS16(gs + k * 256 + j * 4, &stage[cb ^ 1][k * 256]);
        }
        const int tt0 = (c == 0) ? 1 : 0;
        for (int tt = tt0; tt < CH; ++tt) {
            float em_j = stage[cb][tt * NTAG + jj];

            // 48 candidates folded straight into a max3 tree
            float l1[16];
#pragma unroll
            for (int k = 0; k < 16; ++k) {
                float c0 = rl_f32(score, 3 * k)     + trg[3 * k];
                float c1 = rl_f32(score, 3 * k + 1) + trg[3 * k + 1];
                float c2 = rl_f32(score, 3 * k + 2) + trg[3 * k + 2];
                l1[k] = max3(c0, c1, c2);
            }
            float l2[6];
            l2[0] = max3(l1[0],  l1[1],  l1[2]);
            l2[1] = max3(l1[3],  l1[4],  l1[5]);
            l2[2] = max3(l1[6],  l1[7],  l1[8]);
            l2[3] = max3(l1[9],  l1[10], l1[11]);
            l2[4] = max3(l1[12], l1[13], l1[14]);
            l2[5] = l1[15];
            float m0 = max3(l2[0], l2[1], l2[2]);
            float m1 = max3(l2[3], l2[4], l2[5]);
            float best = fmaxf(m0, m1);

            score = best + em_j;                 // S_t[j], exact ref order
            int t = c * CH + tt;
            if (j < NTAG) srb[(size_t)t * NTAG + j] = score;
        }
        asm volatile("s_waitcnt vmcnt(0)" ::: "memory");  // next chunk staged + stores drained
        cb ^= 1;
    }

    // ---------------- final tag: argmax_j(S_{S-1}[j] + end[j]) ----------------
    float fs = (j < NTAG) ? (score + endt[jj]) : NEG_INF;
    float mx = fs;
    mx = fmaxf(mx, __shfl_xor(mx, 32, 64));
    mx = fmaxf(mx, __shfl_xor(mx, 16, 64));
    mx = fmaxf(mx, __shfl_xor(mx,  8, 64));
    mx = fmaxf(mx, __shfl_xor(mx,  4, 64));
    mx = fmaxf(mx, __shfl_xor(mx,  2, 64));
    mx = fmaxf(mx, __shfl_xor(mx,  1, 64));
    unsigned long long bl = __ballot(fs == mx);
    int jt = __ffsll(bl) - 1;                    // first-max (lowest j), exact

    if (j == 0) obuf[SEQ - 1] = jt;

    // ---------------- backtrace: re-derive argmax from staged rows ----------------
    // stage srows chunk NCH-1 (rows 896..1023) — L2-hot, just written
    cb = 0;
    {
        const float* gs = srb + (size_t)(NCH - 1) * CHF;
#pragma unroll
        for (int k = 0; k < NISS; ++k)
            GLDS16(gs + k * 256 + j * 4, &stage[0][k * 256]);
    }
    asm volatile("s_waitcnt vmcnt(0)" ::: "memory");

    for (int rc = NCH - 1; rc >= 0; --rc) {
        if (rc > 0) {
            const float* gs = srb + (size_t)(rc - 1) * CHF;
#pragma unroll
            for (int k = 0; k < NISS; ++k)
                GLDS16(gs + k * 256 + j * 4, &stage[cb ^ 1][k * 256]);
        }
        const int thi = (rc == NCH - 1) ? (SEQ - 1) : (rc * CH + CH);
        const int tlo = rc * CH + 1;
        for (int t = thi; t >= tlo; --t) {
            int lr = (t - 1) - rc * CH;                  // local row index
            float sv = stage[cb][lr * NTAG + jj];        // S_{t-1}[i], lane i
            float tv = Ttr[jt * NTAG + jj];              // T[i][jt], lane i
            float v  = (j < NTAG) ? (sv + tv) : NEG_INF;
            float m  = v;
            m = fmaxf(m, __shfl_xor(m, 32, 64));
            m = fmaxf(m, __shfl_xor(m, 16, 64));
            m = fmaxf(m, __shfl_xor(m,  8, 64));
            m = fmaxf(m, __shfl_xor(m,  4, 64));
            m = fmaxf(m, __shfl_xor(m,  2, 64));
            m = fmaxf(m, __shfl_xor(m,  1, 64));
            unsigned long long b2 = __ballot(v == m);
            jt = __ffsll(b2) - 1;                        // lowest i on ties
            if (j == 0) obuf[t - 1] = jt;
        }
        asm volatile("s_waitcnt vmcnt(0)" ::: "memory");
        cb ^= 1;
    }

    __syncthreads();

    // coalesced int32 dump of the batch's path
    int* outb = out + (size_t)b * SEQ;
#pragma unroll
    for (int t0 = 0; t0 < SEQ / 64; ++t0)
        outb[t0 * 64 + j] = obuf[t0 * 64 + j];
}

extern "C" void kernel_launch(void* const* d_in, const int* in_sizes, int n_in,
                              void* d_out, int out_size, void* d_ws, size_t ws_size,
                              hipStream_t stream) {
    const float* em    = (const float*)d_in[0];
    // d_in[1] = mask (int32), unused — matches reference
    const float* trans = (const float*)d_in[2];
    const float* start = (const float*)d_in[3];
    const float* endt  = (const float*)d_in[4];
    int* out = (int*)d_out;
    float* srows = (float*)d_ws;   // needs B*S*T*4 = 100,663,296 bytes

    crf_viterbi_kernel<<<NBATCH, 64, 0, stream>>>(em, trans, start, endt, out, srows);
}